// Round 1
// baseline (161.804 us; speedup 1.0000x reference)
//
#include <hip/hip_runtime.h>

typedef __attribute__((ext_vector_type(8))) short short8;
typedef __attribute__((ext_vector_type(4))) float f32x4;

#define C_DIM 128
#define K_CODES 1024
#define TOT 8388608   // 16*128*64*64

__device__ __forceinline__ unsigned int f2bf1(float f) {
  unsigned int u = __float_as_uint(f);
  return (u + 0x7FFFu + ((u >> 16) & 1u)) >> 16;   // RNE fp32->bf16
}
__device__ __forceinline__ unsigned int f2bf2(float lo, float hi) {
  return f2bf1(lo) | (f2bf1(hi) << 16);
}

// ---- P1: bf16 codebook + zero used[]/loss ----
__global__ void prep_kernel(const float* __restrict__ cb,
                            unsigned short* __restrict__ ebf,
                            int* __restrict__ used,
                            float* __restrict__ lossp) {
  int gid = blockIdx.x * 256 + threadIdx.x;
  if (gid < K_CODES * C_DIM) ebf[gid] = (unsigned short)f2bf1(cb[gid]);
  if (gid < K_CODES) used[gid] = 0;
  if (gid == 0) *lossp = 0.0f;
}

// ---- P2: ||e_k||^2 in fp32 ----
__global__ void norm_kernel(const float* __restrict__ cb, float* __restrict__ nsq) {
  int k = blockIdx.x * 256 + threadIdx.x;   // grid 4 x 256 = 1024 exact
  float s = 0.f;
  #pragma unroll 8
  for (int c = 0; c < C_DIM; ++c) { float v = cb[k * C_DIM + c]; s += v * v; }
  nsq[k] = s;
}

// ---- M: per-(b,h) block: 64 pixels x 1024 codes argmin + gather + loss ----
// A-frag (16x16x32 bf16): lane L: m=L&15, k=(L>>4)*8+j ; B: n=L&15, k=(L>>4)*8+j
// D: col n = L&15, row m = (L>>4)*4 + reg   [guide §3, m89/m120 verified]
__global__ __launch_bounds__(256, 3)
void vq_main(const float* __restrict__ zin, const float* __restrict__ cb,
             const unsigned short* __restrict__ ebf,
             const float* __restrict__ nsq,
             int* __restrict__ used, float* __restrict__ lossp,
             float* __restrict__ out) {
  __shared__ __align__(16) unsigned char smem[53248];
  uint4* aG = (uint4*)smem;                 // 1024 granules (16 KB): A frags
  uint4* bG = (uint4*)(smem + 16384);       // 2048 granules (32 KB): B frags
  float* nsq_s = (float*)(smem + 49152);    // 4 KB

  const int t  = threadIdx.x;
  const int L  = t & 63;
  const int wv = t >> 6;        // wave id 0..3
  const int q  = L >> 4;        // lane quad
  const int nL = L & 15;

  const int bb = blockIdx.x >> 6;
  const int h  = blockIdx.x & 63;
  const int zbase = bb * (C_DIM * 4096) + h * 64;   // + c*4096 + w

  // stage nsq -> LDS (coalesced)
  for (int i = t; i < K_CODES; i += 256) nsq_s[i] = nsq[i];

  // ---- stage A granules: granule(ks,mt,q,mL) = z[c=ks*32+q*8+j][w=mt*16+mL] bf16
  // index = ks*256 + mt*64 + q*16 + ((mL + 4*(mt+q)) & 15)  (bank-even both ways)
  {
    const int w = t & 63;
    const int mt = w >> 4, mL_ = w & 15;
    #pragma unroll
    for (int p = 0; p < 4; ++p) {
      int oct = p * 4 + (t >> 6);           // wave-uniform -> coalesced loads
      int ks = oct >> 2, qq = oct & 3;
      int c8 = oct * 8;
      float v[8];
      #pragma unroll
      for (int u = 0; u < 8; ++u) v[u] = zin[zbase + (c8 + u) * 4096 + w];
      uint4 val;
      val.x = f2bf2(v[0], v[1]); val.y = f2bf2(v[2], v[3]);
      val.z = f2bf2(v[4], v[5]); val.w = f2bf2(v[6], v[7]);
      int sA = (mL_ + 4 * (mt + qq)) & 15;
      aG[ks * 256 + mt * 64 + qq * 16 + sA] = val;
    }
  }
  __syncthreads();

  // ---- A fragments -> registers (reused across all 64 code tiles)
  short8 afrag[16];
  {
    const short8* ap = (const short8*)aG;
    #pragma unroll
    for (int mt = 0; mt < 4; ++mt)
      #pragma unroll
      for (int ks = 0; ks < 4; ++ks) {
        int sA = (nL + 4 * (mt + q)) & 15;
        afrag[mt * 4 + ks] = ap[ks * 256 + mt * 64 + q * 16 + sA];
      }
  }

  float minv[16]; int mini[16];
  #pragma unroll
  for (int i = 0; i < 16; ++i) { minv[i] = 3.0e38f; mini[i] = 0; }

  const uint4* ebv = (const uint4*)ebf;   // row k = 16 x uint4
  for (int ch = 0; ch < 8; ++ch) {
    const int k0 = ch * 128;
    // stage B chunk: granule(nt,ks,q,nL) = e[k0+nt*16+nL][ks*32+q*8+j]
    // index = nt*256 + ks*64 + nL*4 + q   (bank-even both ways)
    {
      int nLw = t >> 4;           // 0..15
      int oct = t & 15;
      int ks = oct >> 2, qq = oct & 3;
      #pragma unroll
      for (int p = 0; p < 8; ++p) {
        uint4 val = ebv[(k0 + p * 16 + nLw) * 16 + oct];
        bG[p * 256 + ks * 64 + nLw * 4 + qq] = val;
      }
    }
    __syncthreads();
    const short8* bp = (const short8*)bG;
    #pragma unroll
    for (int t2 = 0; t2 < 2; ++t2) {
      const int nt = wv * 2 + t2;
      f32x4 acc0 = {0.f,0.f,0.f,0.f}, acc1 = {0.f,0.f,0.f,0.f};
      f32x4 acc2 = {0.f,0.f,0.f,0.f}, acc3 = {0.f,0.f,0.f,0.f};
      #pragma unroll
      for (int ks = 0; ks < 4; ++ks) {
        short8 bfrag = bp[nt * 256 + ks * 64 + nL * 4 + q];
        acc0 = __builtin_amdgcn_mfma_f32_16x16x32_bf16(afrag[0*4+ks], bfrag, acc0, 0, 0, 0);
        acc1 = __builtin_amdgcn_mfma_f32_16x16x32_bf16(afrag[1*4+ks], bfrag, acc1, 0, 0, 0);
        acc2 = __builtin_amdgcn_mfma_f32_16x16x32_bf16(afrag[2*4+ks], bfrag, acc2, 0, 0, 0);
        ac3:;
        acc3 = __builtin_amdgcn_mfma_f32_16x16x32_bf16(afrag[3*4+ks], bfrag, acc3, 0, 0, 0);
      }
      const int code = k0 + nt * 16 + nL;
      const float nv = nsq_s[code];
      #pragma unroll
      for (int r = 0; r < 4; ++r) {
        float d0 = nv - 2.0f * acc0[r];
        if (d0 < minv[0*4+r]) { minv[0*4+r] = d0; mini[0*4+r] = code; }
        float d1 = nv - 2.0f * acc1[r];
        if (d1 < minv[1*4+r]) { minv[1*4+r] = d1; mini[1*4+r] = code; }
        float d2 = nv - 2.0f * acc2[r];
        if (d2 < minv[2*4+r]) { minv[2*4+r] = d2; mini[2*4+r] = code; }
        float d3 = nv - 2.0f * acc3[r];
        if (d3 < minv[3*4+r]) { minv[3*4+r] = d3; mini[3*4+r] = code; }
      }
    }
    __syncthreads();
  }

  // ---- cross-lane argmin reduction (pad stride 65 -> conflict-free)
  float* redv = (float*)(smem + 16384);           // 64*65 fp32
  int*   redi = (int*)(smem + 16384 + 16640);     // 64*65 int
  #pragma unroll
  for (int mt = 0; mt < 4; ++mt)
    #pragma unroll
    for (int r = 0; r < 4; ++r) {
      int w = mt * 16 + q * 4 + r;     // D-layout row
      int e = wv * 16 + nL;
      redv[w * 65 + e] = minv[mt * 4 + r];
      redi[w * 65 + e] = mini[mt * 4 + r];
    }
  __syncthreads();
  int* widx = (int*)smem;   // aG dead
  if (t < 64) {
    int w = t;
    float bv = redv[w * 65]; int bi = redi[w * 65];
    for (int e = 1; e < 64; ++e) {
      float v = redv[w * 65 + e]; int ii = redi[w * 65 + e];
      if (v < bv || (v == bv && ii < bi)) { bv = v; bi = ii; }  // jnp first-min
    }
    widx[w] = bi;
    used[bi] = 1;
  }
  __syncthreads();

  // ---- fp32 gather z_q + coalesced write + loss partial
  float lsum = 0.f;
  {
    const int w = t & 63, c0 = t >> 6;
    const int idx = widx[w];
    const float* erow = cb + idx * C_DIM;   // per-lane streaming row (L1-hot)
    const int obase = zbase + w;
    #pragma unroll 4
    for (int i = 0; i < 32; ++i) {
      int c = c0 * 32 + i;
      float ev = erow[c];
      int off = obase + c * 4096;
      float zv = zin[off];
      out[off] = ev;                         // lanes over w -> coalesced
      float d = zv - ev;
      lsum += d * d;
    }
  }
  #pragma unroll
  for (int o = 32; o > 0; o >>= 1) lsum += __shfl_down(lsum, o, 64);
  float* wsum = (float*)(smem + 1024);
  if (L == 0) wsum[wv] = lsum;
  __syncthreads();
  if (t == 0) atomicAdd(lossp, wsum[0] + wsum[1] + wsum[2] + wsum[3]);
}

// ---- F: usage count + loss finalize ----
__global__ void finalize_kernel(const int* __restrict__ used,
                                const float* __restrict__ lossp,
                                float* __restrict__ out2) {
  __shared__ int red[256];
  int t = threadIdx.x;
  int s = 0;
  for (int i = t; i < K_CODES; i += 256) s += (used[i] != 0) ? 1 : 0;
  red[t] = s;
  __syncthreads();
  for (int o = 128; o > 0; o >>= 1) {
    if (t < o) red[t] += red[t + o];
    __syncthreads();
  }
  if (t == 0) {
    out2[0] = 1.25f * lossp[0] / 8388608.0f;  // (1+0.25)*MSE
    out2[1] = (float)red[0] / 1024.0f;
  }
}

extern "C" void kernel_launch(void* const* d_in, const int* in_sizes, int n_in,
                              void* d_out, int out_size, void* d_ws, size_t ws_size,
                              hipStream_t stream) {
  const float* z  = (const float*)d_in[0];
  const float* cb = (const float*)d_in[1];
  float* out = (float*)d_out;
  char* ws = (char*)d_ws;
  unsigned short* ebf = (unsigned short*)ws;          // 262144 B
  float* nsq  = (float*)(ws + 262144);                // 4096 B
  int*   used = (int*)(ws + 266240);                  // 4096 B
  float* lossp = (float*)(ws + 270336);               // 4 B

  hipLaunchKernelGGL(prep_kernel, dim3(512), dim3(256), 0, stream, cb, ebf, used, lossp);
  hipLaunchKernelGGL(norm_kernel, dim3(4), dim3(256), 0, stream, cb, nsq);
  hipLaunchKernelGGL(vq_main, dim3(1024), dim3(256), 0, stream,
                     z, cb, ebf, nsq, used, lossp, out);
  hipLaunchKernelGGL(finalize_kernel, dim3(1), dim3(256), 0, stream,
                     used, lossp, out + 8388608);
}